// Round 3
// baseline (364.480 us; speedup 1.0000x reference)
//
#include <hip/hip_runtime.h>

typedef float f32x4 __attribute__((ext_vector_type(4)));
typedef __bf16 bf16x4 __attribute__((ext_vector_type(4)));
typedef __bf16 bf16x8 __attribute__((ext_vector_type(8)));
typedef short s16x4 __attribute__((ext_vector_type(4)));

#define DEVI static __device__ __forceinline__

DEVI f32x4 mfma_k32(bf16x8 a, bf16x8 b, f32x4 c) {
    return __builtin_amdgcn_mfma_f32_16x16x32_bf16(a, b, c, 0, 0, 0);
}

union B4 { bf16x4 h; s16x4 s; };
// 16x16x16 bf16 MFMA: A/B frag k-index = (lane>>4)*4+j == C/D reg layout -> lane-local refragment
DEVI f32x4 mfma_k16(bf16x4 a, bf16x4 b, f32x4 c) {
    B4 ua, ub; ua.h = a; ub.h = b;
    return __builtin_amdgcn_mfma_f32_16x16x16bf16_1k(ua.s, ub.s, c, 0, 0, 0);
}

union F8 { bf16x8 v; bf16x4 h[2]; };

DEVI bf16x8 ld8_lds(const __bf16* p) {   // 16B fragment from LDS (two b64 reads)
    F8 f;
    f.h[0] = *(const bf16x4*)p;
    f.h[1] = *(const bf16x4*)(p + 4);
    return f.v;
}
DEVI bf16x8 ld8_gb(const __bf16* p) { return *(const bf16x8*)p; }  // 16B global
DEVI bf16x8 ldf8(const float* p) {       // 8 fp32 -> bf16x8
    f32x4 a = *(const f32x4*)p;
    f32x4 b = *(const f32x4*)(p + 4);
    F8 f;
#pragma unroll
    for (int j = 0; j < 4; ++j) {
        f.h[0][j] = (__bf16)a[j];
        f.h[1][j] = (__bf16)b[j];
    }
    return f.v;
}
DEVI bf16x4 pk4(f32x4 v) {
    bf16x4 r;
#pragma unroll
    for (int j = 0; j < 4; ++j) r[j] = (__bf16)v[j];
    return r;
}

// ---- pre-kernel: weights fp32 -> bf16, re-tiled into MFMA-fragment order ----
// layout: tile t (16 rows), kc (8 k-chunks of 32), lane l (64), j (8):
//   elem = W[t*16 + (l&15)][kc*32 + (l>>4)*8 + j]  -> flat ((t*8+kc)*64+l)*8+j
// tiles 0..47 = qkv rows 0..767, tiles 48..63 = proj rows 0..255.
__global__ __launch_bounds__(256) void k_w2bf(const float* __restrict__ wqkv,
                                              const float* __restrict__ wp,
                                              __bf16* __restrict__ o) {
    int i = blockIdx.x * 256 + threadIdx.x;      // 32768 threads, one per (t,kc,l)
    int t = i >> 9, kc = (i >> 6) & 7, l = i & 63;
    int row = t * 16 + (l & 15);
    int col = kc * 32 + (l >> 4) * 8;
    const float* src = (t < 48) ? (wqkv + row * 256 + col)
                                : (wp + (row - 768) * 256 + col);
    f32x4 a = *(const f32x4*)src;
    f32x4 b = *(const f32x4*)(src + 4);
    F8 f;
#pragma unroll
    for (int j = 0; j < 4; ++j) { f.h[0][j] = (__bf16)a[j]; f.h[1][j] = (__bf16)b[j]; }
    *(bf16x8*)(o + (size_t)i * 8) = f.v;
}

// ---------------------------------------------------------------------------
// Fused shifted-window attention. 1 block = 1 window, 8 waves = 8 heads.
// 2 barriers; phases serialized to reuse one 32-reg accumulator block.
// Target: total regs <= ~84 -> 6 waves/SIMD -> 3 blocks/CU (LDS 53.9KB fits 3).
// ---------------------------------------------------------------------------
__global__ __launch_bounds__(512, 6) void k_swin(
    const float* __restrict__ x,      // [32,56,56,256] fp32
    const __bf16* __restrict__ wb,    // tiled weights (ws): 64 tiles x 4096
    const float* __restrict__ bqkv,   // [768]
    const float* __restrict__ btab,   // [169,8]
    const float* __restrict__ pbias,  // [256]
    float* __restrict__ out)          // [32,56,56,256] fp32
{
    __shared__ __align__(16) unsigned char smem[53936];
    __bf16* xw = (__bf16*)(smem);                 // [49][260] staged window (bf16)
    __bf16* cb = (__bf16*)(smem + 25480);         // [49][260] ctx (attn output)
    __bf16* tb = (__bf16*)(smem + 50960);         // [8][170] bias table (transposed)
    unsigned* tinfo = (unsigned*)(smem + 53680);  // [64] token code | grp<<8

    const int tid = threadIdx.x;
    const int wid = tid >> 6, lane = tid & 63;
    const int li = lane & 15, g = lane >> 4;
    const int blk = blockIdx.x;
    const int b = blk >> 6, wi = blk & 63;
    const int wh = wi >> 3, ww = wi & 7;
    const int h = wid;                            // wave == head

    // ---- stage shifted window (fp32 -> bf16) ----
    for (int c = tid; c < 49 * 32; c += 512) {
        int tok = c >> 5, part = c & 31;
        int i = tok / 7, j = tok - 7 * i;
        int r = wh * 7 + i + 3;  if (r >= 56) r -= 56;
        int cc = ww * 7 + j + 3; if (cc >= 56) cc -= 56;
        F8 f; f.v = ldf8(x + (((size_t)(b * 56 + r) * 56 + cc) << 8) + (part << 3));
        __bf16* dst = xw + tok * 260 + (part << 3);
        *(bf16x4*)dst = f.h[0];
        *(bf16x4*)(dst + 4) = f.h[1];
    }
    for (int c = tid; c < 169 * 8; c += 512) {       // bias table, transposed
        int idx = c >> 3, hh = c & 7;
        tb[hh * 170 + idx] = (__bf16)btab[c];
    }
    if (tid < 64) {
        int tok = tid;
        if (tok < 49) {
            int i = tok / 7, j = tok - 7 * i;
            unsigned rh = (wh == 7) ? (i < 4 ? 1u : 2u) : 0u;
            unsigned rw = (ww == 7) ? (j < 4 ? 1u : 2u) : 0u;
            tinfo[tok] = (unsigned)(13 * i + j) | ((rh * 3u + rw) << 8);
        } else {
            tinfo[tok] = 255u << 8;
        }
    }
    __syncthreads();   // barrier #1 (xw/tb/tinfo ready; read-only afterwards)

    const f32x4 zf = {0.f, 0.f, 0.f, 0.f};
    const __bf16* wqb = wb + (size_t)(2 * h) * 4096 + lane * 8;  // q tiles 2h,2h+1
    const __bf16* wkb = wqb + 16 * 4096;                          // k tiles +16
    const __bf16* wvb = wqb + 32 * 4096;                          // v tiles +32

    bf16x4 qf[4][2], kf[4][2];   // frags: row=li=tok(16tt+li), k=4g+j=ch(16ct+4g+j)

    // ---- Q GEMM: Q^T = Wq . X^T  (acc[ct][tt]: ch=16ct+4g+r, tok=16tt+li) ----
    {
        f32x4 acc[2][4];
#pragma unroll
        for (int ct = 0; ct < 2; ++ct)
#pragma unroll
            for (int tt = 0; tt < 4; ++tt) acc[ct][tt] = zf;
#pragma unroll
        for (int kc = 0; kc < 8; ++kc) {
            bf16x8 xf[4];
#pragma unroll
            for (int tt = 0; tt < 4; ++tt) {
                int row = 16 * tt + li; if (row > 48) row = 48;
                xf[tt] = ld8_lds(xw + row * 260 + kc * 32 + g * 8);
            }
#pragma unroll
            for (int ct = 0; ct < 2; ++ct) {
                bf16x8 aq = ld8_gb(wqb + ct * 4096 + kc * 512);
#pragma unroll
                for (int tt = 0; tt < 4; ++tt)
                    acc[ct][tt] = mfma_k32(aq, xf[tt], acc[ct][tt]);
            }
        }
#pragma unroll
        for (int ct = 0; ct < 2; ++ct) {
            f32x4 bq = *(const f32x4*)(bqkv + h * 32 + 16 * ct + 4 * g);
#pragma unroll
            for (int tt = 0; tt < 4; ++tt)
#pragma unroll
                for (int r = 0; r < 4; ++r)
                    qf[tt][ct][r] = (__bf16)((acc[ct][tt][r] + bq[r]) * 0.17677669529663687f);
        }
    }
    __builtin_amdgcn_sched_barrier(0);

    // ---- K GEMM (reuses accumulator block) ----
    {
        f32x4 acc[2][4];
#pragma unroll
        for (int ct = 0; ct < 2; ++ct)
#pragma unroll
            for (int tt = 0; tt < 4; ++tt) acc[ct][tt] = zf;
#pragma unroll
        for (int kc = 0; kc < 8; ++kc) {
            bf16x8 xf[4];
#pragma unroll
            for (int tt = 0; tt < 4; ++tt) {
                int row = 16 * tt + li; if (row > 48) row = 48;
                xf[tt] = ld8_lds(xw + row * 260 + kc * 32 + g * 8);
            }
#pragma unroll
            for (int ct = 0; ct < 2; ++ct) {
                bf16x8 ak = ld8_gb(wkb + ct * 4096 + kc * 512);
#pragma unroll
                for (int tt = 0; tt < 4; ++tt)
                    acc[ct][tt] = mfma_k32(ak, xf[tt], acc[ct][tt]);
            }
        }
#pragma unroll
        for (int ct = 0; ct < 2; ++ct) {
            f32x4 bk = *(const f32x4*)(bqkv + 256 + h * 32 + 16 * ct + 4 * g);
#pragma unroll
            for (int tt = 0; tt < 4; ++tt)
#pragma unroll
                for (int r = 0; r < 4; ++r)
                    kf[tt][ct][r] = (__bf16)(acc[ct][tt][r] + bk[r]);
        }
    }
    __builtin_amdgcn_sched_barrier(0);

    // ---- fused S + softmax, one q-tile at a time -> pf ----
    unsigned pkk[8];   // kt-side token info, 2 x u16 per reg
#pragma unroll
    for (int kt = 0; kt < 4; ++kt)
#pragma unroll
        for (int rp = 0; rp < 2; ++rp)
            pkk[kt * 2 + rp] = tinfo[16 * kt + 4 * g + 2 * rp]
                             | (tinfo[16 * kt + 4 * g + 2 * rp + 1] << 16);

    const __bf16* tbh = tb + h * 170 + 84;
    bf16x4 pf[4][4];   // P frags [qt][kt]: row=li=q, k=4g+j=key
#pragma unroll
    for (int qt = 0; qt < 4; ++qt) {
        f32x4 sv[4];   // S^T frags: lane holds key=16kt+4g+r, q=16qt+li
#pragma unroll
        for (int kt = 0; kt < 4; ++kt) {
            f32x4 acc = zf;
            acc = mfma_k16(kf[kt][0], qf[qt][0], acc);
            acc = mfma_k16(kf[kt][1], qf[qt][1], acc);
            sv[kt] = acc;
        }
        unsigned inN = tinfo[16 * qt + li];
        int cN = (int)(inN & 255u);
        float mx = -1e30f;
#pragma unroll
        for (int kt = 0; kt < 4; ++kt)
#pragma unroll
            for (int r = 0; r < 4; ++r) {
                unsigned m = (pkk[kt * 2 + (r >> 1)] >> (16 * (r & 1))) & 0xffffu;
                float v = sv[kt][r] + (float)tbh[cN - (int)(m & 255u)]
                        + ((((inN ^ m) & 0xff00u) != 0u) ? -100.f : 0.f);
                if (kt == 3 && (r > 0 || g > 0)) v = -30000.f;   // keys >= 49
                sv[kt][r] = v;
                mx = fmaxf(mx, v);
            }
        mx = fmaxf(mx, __shfl_xor(mx, 16));
        mx = fmaxf(mx, __shfl_xor(mx, 32));
        float sum = 0.f;
#pragma unroll
        for (int kt = 0; kt < 4; ++kt)
#pragma unroll
            for (int r = 0; r < 4; ++r) {
                float e = __expf(sv[kt][r] - mx);
                sv[kt][r] = e;
                sum += e;
            }
        sum += __shfl_xor(sum, 16);
        sum += __shfl_xor(sum, 32);
        float inv = 1.0f / sum;
#pragma unroll
        for (int kt = 0; kt < 4; ++kt) {
            bf16x4 pp;
#pragma unroll
            for (int r = 0; r < 4; ++r) pp[r] = (__bf16)(sv[kt][r] * inv);
            pf[qt][kt] = pp;
        }
    }
    __builtin_amdgcn_sched_barrier(0);

    // ---- V GEMM: V = X . Wv^T (va[tt][ct]: tok=16tt+4g+r, ch=16ct+li) ----
    bf16x4 vf[2][4];   // V^T frags [dt][kt]: row=li=d, k=4g+j=key
    {
        f32x4 acc[4][2];
#pragma unroll
        for (int tt = 0; tt < 4; ++tt)
#pragma unroll
            for (int ct = 0; ct < 2; ++ct) acc[tt][ct] = zf;
#pragma unroll
        for (int kc = 0; kc < 8; ++kc) {
            bf16x8 bv0 = ld8_gb(wvb + kc * 512);
            bf16x8 bv1 = ld8_gb(wvb + 4096 + kc * 512);
#pragma unroll
            for (int tt = 0; tt < 4; ++tt) {
                int row = 16 * tt + li; if (row > 48) row = 48;
                bf16x8 xf = ld8_lds(xw + row * 260 + kc * 32 + g * 8);
                acc[tt][0] = mfma_k32(xf, bv0, acc[tt][0]);
                acc[tt][1] = mfma_k32(xf, bv1, acc[tt][1]);
            }
        }
#pragma unroll
        for (int ct = 0; ct < 2; ++ct) {
            float bv = bqkv[512 + h * 32 + 16 * ct + li];
#pragma unroll
            for (int tt = 0; tt < 4; ++tt)
#pragma unroll
                for (int r = 0; r < 4; ++r)
                    vf[ct][tt][r] = (__bf16)(acc[tt][ct][r] + bv);
        }
    }
    __builtin_amdgcn_sched_barrier(0);

    // ---- PV: per-qt, eager bf16 convert (oa never fully live) ----
    bf16x4 osv[4][2];  // ctx frags [qt][dt]: q=16qt+4g+r, d=16dt+li
#pragma unroll
    for (int qt = 0; qt < 4; ++qt)
#pragma unroll
        for (int dt = 0; dt < 2; ++dt) {
            f32x4 acc = zf;
#pragma unroll
            for (int kt = 0; kt < 4; ++kt)
                acc = mfma_k16(pf[qt][kt], vf[dt][kt], acc);
            osv[qt][dt] = pk4(acc);
        }

    // ---- ctx scatter -> cb ----
#pragma unroll
    for (int qt = 0; qt < 4; ++qt)
#pragma unroll
        for (int r = 0; r < 4; ++r) {
            int q = 16 * qt + 4 * g + r;
            if (q < 49) {
#pragma unroll
                for (int dt = 0; dt < 2; ++dt)
                    cb[q * 260 + 32 * h + 16 * dt + li] = osv[qt][dt][r];
            }
        }
    __syncthreads();   // barrier #2 (ctx complete)

    // ---- proj: 8 waves, wave = (pm: 32 rows, pn: 64 cols) ----
    const int pm = wid >> 2, pn = wid & 3;
    f32x4 pacc[2][4];
#pragma unroll
    for (int mt = 0; mt < 2; ++mt)
#pragma unroll
        for (int nt = 0; nt < 4; ++nt) pacc[mt][nt] = zf;

    const __bf16* wpb = wb + (size_t)(48 + 4 * pn) * 4096 + lane * 8;
#pragma unroll
    for (int kc = 0; kc < 8; ++kc) {
        bf16x8 a[2];
#pragma unroll
        for (int mt = 0; mt < 2; ++mt) {
            int row = 32 * pm + 16 * mt + li; if (row > 48) row = 48;
            a[mt] = ld8_lds(cb + row * 260 + kc * 32 + g * 8);
        }
#pragma unroll
        for (int nt = 0; nt < 4; ++nt) {
            bf16x8 bb = ld8_gb(wpb + nt * 4096 + kc * 512);
#pragma unroll
            for (int mt = 0; mt < 2; ++mt)
                pacc[mt][nt] = mfma_k32(a[mt], bb, pacc[mt][nt]);
        }
    }

    // ---- epilogue: bias + direct fp32 scatter (un-window + roll-back) ----
#pragma unroll
    for (int nt = 0; nt < 4; ++nt) {
        int o = 64 * pn + 16 * nt + li;
        float bias = pbias[o];
#pragma unroll
        for (int mt = 0; mt < 2; ++mt)
#pragma unroll
            for (int r = 0; r < 4; ++r) {
                int n = 32 * pm + 16 * mt + 4 * g + r;
                if (n < 49) {
                    int i = n / 7, j = n - 7 * i;
                    int rr = wh * 7 + i + 3; if (rr >= 56) rr -= 56;
                    int cc = ww * 7 + j + 3; if (cc >= 56) cc -= 56;
                    out[(((size_t)(b * 56 + rr) * 56 + cc) << 8) + o] =
                        pacc[mt][nt][r] + bias;
                }
            }
    }
}

extern "C" void kernel_launch(void* const* d_in, const int* in_sizes, int n_in,
                              void* d_out, int out_size, void* d_ws, size_t ws_size,
                              hipStream_t stream) {
    const float* x    = (const float*)d_in[0];
    const float* wqkv = (const float*)d_in[1];
    const float* bqkv = (const float*)d_in[2];
    const float* wp   = (const float*)d_in[3];
    const float* pb   = (const float*)d_in[4];
    const float* btab = (const float*)d_in[5];
    float* out = (float*)d_out;

    __bf16* wbuf = (__bf16*)d_ws;            // 262,144 bf16 = 512 KB
    k_w2bf<<<128, 256, 0, stream>>>(wqkv, wp, wbuf);
    k_swin<<<2048, 512, 0, stream>>>(x, wbuf, bqkv, btab, pb, out);
}

// Round 4
// 297.037 us; speedup vs baseline: 1.2271x; 1.2271x over previous
//
#include <hip/hip_runtime.h>

typedef float f32x4 __attribute__((ext_vector_type(4)));
typedef __bf16 bf16x4 __attribute__((ext_vector_type(4)));
typedef __bf16 bf16x8 __attribute__((ext_vector_type(8)));
typedef short s16x4 __attribute__((ext_vector_type(4)));

#define DEVI static __device__ __forceinline__

DEVI f32x4 mfma_k32(bf16x8 a, bf16x8 b, f32x4 c) {
    return __builtin_amdgcn_mfma_f32_16x16x32_bf16(a, b, c, 0, 0, 0);
}

union B4 { bf16x4 h; s16x4 s; };
// 16x16x16 bf16 MFMA: A/B frag k-index = (lane>>4)*4+j == C/D reg layout -> lane-local refragment
DEVI f32x4 mfma_k16(bf16x4 a, bf16x4 b, f32x4 c) {
    B4 ua, ub; ua.h = a; ub.h = b;
    return __builtin_amdgcn_mfma_f32_16x16x16bf16_1k(ua.s, ub.s, c, 0, 0, 0);
}

union F8 { bf16x8 v; bf16x4 h[2]; };

DEVI bf16x8 ld8_lds(const __bf16* p) {   // 16B fragment from LDS (two b64 reads)
    F8 f;
    f.h[0] = *(const bf16x4*)p;
    f.h[1] = *(const bf16x4*)(p + 4);
    return f.v;
}
DEVI bf16x8 ld8_gb(const __bf16* p) { return *(const bf16x8*)p; }  // 16B global
DEVI bf16x8 ldf8(const float* p) {       // 8 fp32 -> bf16x8
    f32x4 a = *(const f32x4*)p;
    f32x4 b = *(const f32x4*)(p + 4);
    F8 f;
#pragma unroll
    for (int j = 0; j < 4; ++j) {
        f.h[0][j] = (__bf16)a[j];
        f.h[1][j] = (__bf16)b[j];
    }
    return f.v;
}

// ---- pre-kernel (merged):
// blocks 0..127: weights fp32 -> bf16, re-tiled into MFMA-fragment order.
//   elem = W[t*16 + (l&15)][kc*32 + (l>>4)*8 + j] -> flat ((t*8+kc)*64+l)*8+j
//   tiles 0..47 = qkv rows 0..767, tiles 48..63 = proj rows 0..255.
// blocks 128..639: bias+mask table bm[cls][h][qt][kt][lane][r] f32 (512 KB),
//   fragment-ordered: value for (q=16qt+(lane&15), key=16kt+4*(lane>>4)+r).
__global__ __launch_bounds__(256) void k_pre(const float* __restrict__ wqkv,
                                             const float* __restrict__ wp,
                                             const float* __restrict__ btab,
                                             __bf16* __restrict__ wout,
                                             float* __restrict__ bmout) {
    int bid = blockIdx.x;
    if (bid < 128) {
        int i = bid * 256 + threadIdx.x;             // one per (t,kc,l)
        int t = i >> 9, kc = (i >> 6) & 7, l = i & 63;
        int row = t * 16 + (l & 15);
        int col = kc * 32 + (l >> 4) * 8;
        const float* src = (t < 48) ? (wqkv + row * 256 + col)
                                    : (wp + (row - 768) * 256 + col);
        f32x4 a = *(const f32x4*)src;
        f32x4 b = *(const f32x4*)(src + 4);
        F8 f;
#pragma unroll
        for (int j = 0; j < 4; ++j) { f.h[0][j] = (__bf16)a[j]; f.h[1][j] = (__bf16)b[j]; }
        *(bf16x8*)(wout + (size_t)i * 8) = f.v;
    } else {
        int i = (bid - 128) * 256 + threadIdx.x;     // 0..131071
        int r = i & 3, lane = (i >> 2) & 63;
        int kt = (i >> 8) & 3, qt = (i >> 10) & 3, h = (i >> 12) & 7, cls = i >> 15;
        int li = lane & 15, g = lane >> 4;
        int q = 16 * qt + li;
        int key = 16 * kt + 4 * g + r;
        float v;
        if (key >= 49) {
            v = -30000.f;                            // pad keys: masked for all rows
        } else if (q >= 49) {
            v = 0.f;                                 // pad q rows: don't-care
        } else {
            int qi = q / 7, qj = q - 7 * qi;
            int ki = key / 7, kj = key - 7 * ki;
            float bias = btab[((qi - ki + 6) * 13 + (qj - kj + 6)) * 8 + h];
            int ch = cls >> 1, cw = cls & 1;
            int gq = (ch ? (qi < 4 ? 1 : 2) : 0) * 3 + (cw ? (qj < 4 ? 1 : 2) : 0);
            int gk = (ch ? (ki < 4 ? 1 : 2) : 0) * 3 + (cw ? (kj < 4 ? 1 : 2) : 0);
            v = bias + ((gq != gk) ? -100.f : 0.f);
        }
        bmout[i] = v;
    }
}

// ---------------------------------------------------------------------------
// Fused shifted-window attention. 1 block = 1 window, 8 waves = 8 heads.
// 2 barriers; attention fully register-resident per wave; bias+mask table
// precomputed per window-class in fragment order (no per-element mask ALU).
// ---------------------------------------------------------------------------
__global__ __launch_bounds__(512)
__attribute__((amdgpu_waves_per_eu(4))) void k_swin(
    const float* __restrict__ x,      // [32,56,56,256] fp32
    const __bf16* __restrict__ wb,    // tiled weights (ws): 64 tiles x 4096
    const float* __restrict__ bqkv,   // [768]
    const float* __restrict__ bm,     // [4][8][4][4][64][4] f32 bias+mask table
    const float* __restrict__ pbias,  // [256]
    float* __restrict__ out)          // [32,56,56,256] fp32
{
    __shared__ __align__(16) unsigned char smem[51216];
    __bf16* xw = (__bf16*)(smem);                 // [49][260] staged window (bf16)
    __bf16* cb = (__bf16*)(smem + 25480);         // [49][260] ctx (attn output)
    unsigned* obase = (unsigned*)(smem + 50960);  // [49] output base offsets

    const int tid = threadIdx.x;
    const int wid = tid >> 6, lane = tid & 63;
    const int li = lane & 15, g = lane >> 4;
    const int blk = blockIdx.x;
    const int b = blk >> 6, wi = blk & 63;
    const int wh = wi >> 3, ww = wi & 7;
    const int h = wid;                            // wave == head
    const int cls = ((wh == 7) ? 2 : 0) + ((ww == 7) ? 1 : 0);

    // ---- stage shifted window (fp32 -> bf16) ----
    for (int c = tid; c < 49 * 32; c += 512) {
        int tok = c >> 5, part = c & 31;
        int i = tok / 7, j = tok - 7 * i;
        int r = wh * 7 + i + 3;  if (r >= 56) r -= 56;
        int cc = ww * 7 + j + 3; if (cc >= 56) cc -= 56;
        F8 f; f.v = ldf8(x + (((size_t)(b * 56 + r) * 56 + cc) << 8) + (part << 3));
        __bf16* dst = xw + tok * 260 + (part << 3);
        *(bf16x4*)dst = f.h[0];
        *(bf16x4*)(dst + 4) = f.h[1];
    }
    if (tid < 49) {                                  // output base addresses
        int i = tid / 7, j = tid - 7 * i;
        int r = wh * 7 + i + 3;  if (r >= 56) r -= 56;
        int cc = ww * 7 + j + 3; if (cc >= 56) cc -= 56;
        obase[tid] = ((unsigned)((b * 56 + r) * 56 + cc)) << 8;
    }
    __syncthreads();   // barrier #1 (xw/obase ready; read-only afterwards)

    const f32x4 zf = {0.f, 0.f, 0.f, 0.f};
    const __bf16* wqb = wb + (size_t)(2 * h) * 4096 + lane * 8;  // q tiles 2h,2h+1
    const __bf16* wkb = wqb + 16 * 4096;                          // k tiles +16
    const __bf16* wvb = wqb + 32 * 4096;                          // v tiles +32

    // ---- Q,K GEMM (interleaved): acc[ct][tt]: ch=16ct+4g+r, tok=16tt+li ----
    f32x4 qa[2][4], ka[2][4];
#pragma unroll
    for (int ct = 0; ct < 2; ++ct)
#pragma unroll
        for (int tt = 0; tt < 4; ++tt) { qa[ct][tt] = zf; ka[ct][tt] = zf; }

#pragma unroll
    for (int kc = 0; kc < 8; ++kc) {
        bf16x8 xf[4];
#pragma unroll
        for (int tt = 0; tt < 4; ++tt) {
            int row = 16 * tt + li; if (row > 48) row = 48;   // clamp pad rows
            xf[tt] = ld8_lds(xw + row * 260 + kc * 32 + g * 8);
        }
#pragma unroll
        for (int ct = 0; ct < 2; ++ct) {
            bf16x8 aq = ld8_gb(wqb + ct * 4096 + kc * 512);
            bf16x8 ak = ld8_gb(wkb + ct * 4096 + kc * 512);
#pragma unroll
            for (int tt = 0; tt < 4; ++tt) {
                qa[ct][tt] = mfma_k32(aq, xf[tt], qa[ct][tt]);
                ka[ct][tt] = mfma_k32(ak, xf[tt], ka[ct][tt]);
            }
        }
    }

    // lane-local refragment: qf/kf[tt][ct]: row=li=tok(16tt+li), k=4g+j=ch(16ct+4g+j)
    bf16x4 qf[4][2], kf[4][2];
#pragma unroll
    for (int ct = 0; ct < 2; ++ct) {
        f32x4 bq = *(const f32x4*)(bqkv + h * 32 + 16 * ct + 4 * g);
        f32x4 bk = *(const f32x4*)(bqkv + 256 + h * 32 + 16 * ct + 4 * g);
#pragma unroll
        for (int tt = 0; tt < 4; ++tt)
#pragma unroll
            for (int r = 0; r < 4; ++r) {
                qf[tt][ct][r] = (__bf16)((qa[ct][tt][r] + bq[r]) * 0.17677669529663687f);
                kf[tt][ct][r] = (__bf16)(ka[ct][tt][r] + bk[r]);
            }
    }

    // ---- fused S + softmax, one q-tile at a time -> pf ----
    const float* bmq = bm + cls * 32768 + h * 4096 + lane * 4;
    bf16x4 pf[4][4];   // P frags [qt][kt]: row=li=q, k=4g+j=key
#pragma unroll
    for (int qt = 0; qt < 4; ++qt) {
        f32x4 sv[4];   // S^T frags: lane holds key=16kt+4g+r, q=16qt+li
#pragma unroll
        for (int kt = 0; kt < 4; ++kt) {
            f32x4 acc = zf;
            acc = mfma_k16(kf[kt][0], qf[qt][0], acc);
            acc = mfma_k16(kf[kt][1], qf[qt][1], acc);
            sv[kt] = acc;
        }
#pragma unroll
        for (int kt = 0; kt < 4; ++kt)
            sv[kt] += *(const f32x4*)(bmq + qt * 1024 + kt * 256);  // bias+mask
        float mx = -1e30f;
#pragma unroll
        for (int kt = 0; kt < 4; ++kt)
#pragma unroll
            for (int r = 0; r < 4; ++r) mx = fmaxf(mx, sv[kt][r]);
        mx = fmaxf(mx, __shfl_xor(mx, 16));
        mx = fmaxf(mx, __shfl_xor(mx, 32));
        float sum = 0.f;
#pragma unroll
        for (int kt = 0; kt < 4; ++kt)
#pragma unroll
            for (int r = 0; r < 4; ++r) {
                float e = __expf(sv[kt][r] - mx);
                sv[kt][r] = e;
                sum += e;
            }
        sum += __shfl_xor(sum, 16);
        sum += __shfl_xor(sum, 32);
        float inv = 1.0f / sum;
#pragma unroll
        for (int kt = 0; kt < 4; ++kt) {
            bf16x4 pp;
#pragma unroll
            for (int r = 0; r < 4; ++r) pp[r] = (__bf16)(sv[kt][r] * inv);
            pf[qt][kt] = pp;
        }
    }
    __builtin_amdgcn_sched_barrier(0);   // fence: keep V-GEMM out of softmax pressure

    // ---- V GEMM: V = X . Wv^T (va[tt][ct]: tok=16tt+4g+r, ch=16ct+li) ----
    f32x4 va[4][2];
#pragma unroll
    for (int tt = 0; tt < 4; ++tt)
#pragma unroll
        for (int ct = 0; ct < 2; ++ct) va[tt][ct] = zf;
#pragma unroll
    for (int kc = 0; kc < 8; ++kc) {
        bf16x8 xf[4];
#pragma unroll
        for (int tt = 0; tt < 4; ++tt) {
            int row = 16 * tt + li; if (row > 48) row = 48;
            xf[tt] = ld8_lds(xw + row * 260 + kc * 32 + g * 8);
        }
#pragma unroll
        for (int ct = 0; ct < 2; ++ct) {
            bf16x8 bv = ld8_gb(wvb + ct * 4096 + kc * 512);
#pragma unroll
            for (int tt = 0; tt < 4; ++tt)
                va[tt][ct] = mfma_k32(xf[tt], bv, va[tt][ct]);
        }
    }
    bf16x4 vf[2][4];   // V^T frags [dt][kt]: row=li=d, k=4g+j=key
#pragma unroll
    for (int ct = 0; ct < 2; ++ct) {
        float bv = bqkv[512 + h * 32 + 16 * ct + li];
#pragma unroll
        for (int tt = 0; tt < 4; ++tt)
#pragma unroll
            for (int r = 0; r < 4; ++r)
                vf[ct][tt][r] = (__bf16)(va[tt][ct][r] + bv);
    }

    // ---- PV: out[qt][dt]: lane holds q=16qt+4g+r, d=16dt+li ----
    f32x4 oa[4][2];
#pragma unroll
    for (int qt = 0; qt < 4; ++qt)
#pragma unroll
        for (int dt = 0; dt < 2; ++dt) {
            f32x4 acc = zf;
#pragma unroll
            for (int kt = 0; kt < 4; ++kt)
                acc = mfma_k16(pf[qt][kt], vf[dt][kt], acc);
            oa[qt][dt] = acc;
        }

    // ---- ctx scatter -> cb ----
#pragma unroll
    for (int qt = 0; qt < 4; ++qt)
#pragma unroll
        for (int r = 0; r < 4; ++r) {
            int q = 16 * qt + 4 * g + r;
            if (q < 49) {
#pragma unroll
                for (int dt = 0; dt < 2; ++dt)
                    cb[q * 260 + 32 * h + 16 * dt + li] = (__bf16)oa[qt][dt][r];
            }
        }
    __syncthreads();   // barrier #2 (ctx complete)

    // ---- proj: 8 waves, wave = (pm: 32 rows, pn: 64 cols) ----
    const int pm = wid >> 2, pn = wid & 3;
    f32x4 pacc[2][4];
#pragma unroll
    for (int mt = 0; mt < 2; ++mt)
#pragma unroll
        for (int nt = 0; nt < 4; ++nt) pacc[mt][nt] = zf;

    const __bf16* wpb = wb + (size_t)(48 + 4 * pn) * 4096 + lane * 8;
#pragma unroll
    for (int kc = 0; kc < 8; ++kc) {
        bf16x8 a[2];
#pragma unroll
        for (int mt = 0; mt < 2; ++mt) {
            int row = 32 * pm + 16 * mt + li; if (row > 48) row = 48;
            a[mt] = ld8_lds(cb + row * 260 + kc * 32 + g * 8);
        }
#pragma unroll
        for (int nt = 0; nt < 4; ++nt) {
            bf16x8 bb = ld8_gb(wpb + nt * 4096 + kc * 512);
#pragma unroll
            for (int mt = 0; mt < 2; ++mt)
                pacc[mt][nt] = mfma_k32(a[mt], bb, pacc[mt][nt]);
        }
    }

    // ---- epilogue: bias + direct fp32 scatter via obase LUT ----
#pragma unroll
    for (int nt = 0; nt < 4; ++nt) {
        int o = 64 * pn + 16 * nt + li;
        float bias = pbias[o];
#pragma unroll
        for (int mt = 0; mt < 2; ++mt)
#pragma unroll
            for (int r = 0; r < 4; ++r) {
                int n = 32 * pm + 16 * mt + 4 * g + r;
                if (n < 49)
                    out[obase[n] + (unsigned)o] = pacc[mt][nt][r] + bias;
            }
    }
}

extern "C" void kernel_launch(void* const* d_in, const int* in_sizes, int n_in,
                              void* d_out, int out_size, void* d_ws, size_t ws_size,
                              hipStream_t stream) {
    const float* x    = (const float*)d_in[0];
    const float* wqkv = (const float*)d_in[1];
    const float* bqkv = (const float*)d_in[2];
    const float* wp   = (const float*)d_in[3];
    const float* pb   = (const float*)d_in[4];
    const float* btab = (const float*)d_in[5];
    float* out = (float*)d_out;

    __bf16* wbuf = (__bf16*)d_ws;                       // 512 KB weights (bf16)
    float* bm = (float*)((char*)d_ws + 524288);         // 512 KB bias+mask table
    k_pre<<<640, 256, 0, stream>>>(wqkv, wp, btab, wbuf, bm);
    k_swin<<<2048, 512, 0, stream>>>(x, wbuf, bqkv, bm, pb, out);
}

// Round 5
// 275.750 us; speedup vs baseline: 1.3218x; 1.0772x over previous
//
#include <hip/hip_runtime.h>

typedef float f32x4 __attribute__((ext_vector_type(4)));
typedef __bf16 bf16x4 __attribute__((ext_vector_type(4)));
typedef __bf16 bf16x8 __attribute__((ext_vector_type(8)));
typedef short s16x4 __attribute__((ext_vector_type(4)));

#define DEVI static __device__ __forceinline__

DEVI f32x4 mfma_k32(bf16x8 a, bf16x8 b, f32x4 c) {
    return __builtin_amdgcn_mfma_f32_16x16x32_bf16(a, b, c, 0, 0, 0);
}

union B4 { bf16x4 h; s16x4 s; };
// 16x16x16 bf16 MFMA: A/B frag k-index = (lane>>4)*4+j == C/D reg layout -> lane-local refragment
DEVI f32x4 mfma_k16(bf16x4 a, bf16x4 b, f32x4 c) {
    B4 ua, ub; ua.h = a; ub.h = b;
    return __builtin_amdgcn_mfma_f32_16x16x16bf16_1k(ua.s, ub.s, c, 0, 0, 0);
}

union F8 { bf16x8 v; bf16x4 h[2]; };

DEVI bf16x8 ld8_lds(const __bf16* p) {   // 16B fragment from LDS (two b64 reads)
    F8 f;
    f.h[0] = *(const bf16x4*)p;
    f.h[1] = *(const bf16x4*)(p + 4);
    return f.v;
}
DEVI bf16x8 ld8_gb(const __bf16* p) { return *(const bf16x8*)p; }  // 16B global
DEVI bf16x8 ldf8(const float* p) {       // 8 fp32 -> bf16x8
    f32x4 a = *(const f32x4*)p;
    f32x4 b = *(const f32x4*)(p + 4);
    F8 f;
#pragma unroll
    for (int j = 0; j < 4; ++j) {
        f.h[0][j] = (__bf16)a[j];
        f.h[1][j] = (__bf16)b[j];
    }
    return f.v;
}
DEVI bf16x4 pk4(f32x4 v) {
    bf16x4 r;
#pragma unroll
    for (int j = 0; j < 4; ++j) r[j] = (__bf16)v[j];
    return r;
}

// ---- pre-kernel (merged):
// blocks 0..127: weights fp32 -> bf16, re-tiled into MFMA-fragment order.
//   elem = W[t*16 + (l&15)][kc*32 + (l>>4)*8 + j] -> flat ((t*8+kc)*64+l)*8+j
//   tiles 0..47 = qkv rows 0..767, tiles 48..63 = proj rows 0..255.
// blocks 128..639: bias+mask table bm[cls][h][qt][kt][lane][r] f32 (512 KB),
//   fragment-ordered: value for (q=16qt+(lane&15), key=16kt+4*(lane>>4)+r).
__global__ __launch_bounds__(256) void k_pre(const float* __restrict__ wqkv,
                                             const float* __restrict__ wp,
                                             const float* __restrict__ btab,
                                             __bf16* __restrict__ wout,
                                             float* __restrict__ bmout) {
    int bid = blockIdx.x;
    if (bid < 128) {
        int i = bid * 256 + threadIdx.x;             // one per (t,kc,l)
        int t = i >> 9, kc = (i >> 6) & 7, l = i & 63;
        int row = t * 16 + (l & 15);
        int col = kc * 32 + (l >> 4) * 8;
        const float* src = (t < 48) ? (wqkv + row * 256 + col)
                                    : (wp + (row - 768) * 256 + col);
        f32x4 a = *(const f32x4*)src;
        f32x4 b = *(const f32x4*)(src + 4);
        F8 f;
#pragma unroll
        for (int j = 0; j < 4; ++j) { f.h[0][j] = (__bf16)a[j]; f.h[1][j] = (__bf16)b[j]; }
        *(bf16x8*)(wout + (size_t)i * 8) = f.v;
    } else {
        int i = (bid - 128) * 256 + threadIdx.x;     // 0..131071
        int r = i & 3, lane = (i >> 2) & 63;
        int kt = (i >> 8) & 3, qt = (i >> 10) & 3, h = (i >> 12) & 7, cls = i >> 15;
        int li = lane & 15, g = lane >> 4;
        int q = 16 * qt + li;
        int key = 16 * kt + 4 * g + r;
        float v;
        if (key >= 49) {
            v = -30000.f;                            // pad keys: masked for all rows
        } else if (q >= 49) {
            v = 0.f;                                 // pad q rows: don't-care
        } else {
            int qi = q / 7, qj = q - 7 * qi;
            int ki = key / 7, kj = key - 7 * ki;
            float bias = btab[((qi - ki + 6) * 13 + (qj - kj + 6)) * 8 + h];
            int ch = cls >> 1, cw = cls & 1;
            int gq = (ch ? (qi < 4 ? 1 : 2) : 0) * 3 + (cw ? (qj < 4 ? 1 : 2) : 0);
            int gk = (ch ? (ki < 4 ? 1 : 2) : 0) * 3 + (cw ? (kj < 4 ? 1 : 2) : 0);
            v = bias + ((gq != gk) ? -100.f : 0.f);
        }
        bmout[i] = v;
    }
}

// ---------------------------------------------------------------------------
// Fused shifted-window attention. 1 block = 1 window, 8 waves = 8 heads.
// 2 barriers; attention register-resident; phase order QK -> V -> fused
// per-qt {S, softmax, PV} so independent MFMA work overlaps softmax chains.
// ---------------------------------------------------------------------------
__global__ __launch_bounds__(512)
__attribute__((amdgpu_waves_per_eu(4))) void k_swin(
    const float* __restrict__ x,      // [32,56,56,256] fp32
    const __bf16* __restrict__ wb,    // tiled weights (ws): 64 tiles x 4096
    const float* __restrict__ bqkv,   // [768]
    const float* __restrict__ bm,     // [4][8][4][4][64][4] f32 bias+mask table
    const float* __restrict__ pbias,  // [256]
    float* __restrict__ out)          // [32,56,56,256] fp32
{
    __shared__ __align__(16) unsigned char smem[51216];
    __bf16* xw = (__bf16*)(smem);                 // [49][260] staged window (bf16)
    __bf16* cb = (__bf16*)(smem + 25480);         // [49][260] ctx (attn output)
    unsigned* obase = (unsigned*)(smem + 50960);  // [49] output base offsets

    const int tid = threadIdx.x;
    const int wid = tid >> 6, lane = tid & 63;
    const int li = lane & 15, g = lane >> 4;
    const int blk = blockIdx.x;
    const int b = blk >> 6, wi = blk & 63;
    const int wh = wi >> 3, ww = wi & 7;
    const int h = wid;                            // wave == head
    const int cls = ((wh == 7) ? 2 : 0) + ((ww == 7) ? 1 : 0);

    // ---- stage shifted window (fp32 -> bf16) ----
    for (int c = tid; c < 49 * 32; c += 512) {
        int tok = c >> 5, part = c & 31;
        int i = tok / 7, j = tok - 7 * i;
        int r = wh * 7 + i + 3;  if (r >= 56) r -= 56;
        int cc = ww * 7 + j + 3; if (cc >= 56) cc -= 56;
        F8 f; f.v = ldf8(x + (((size_t)(b * 56 + r) * 56 + cc) << 8) + (part << 3));
        __bf16* dst = xw + tok * 260 + (part << 3);
        *(bf16x4*)dst = f.h[0];
        *(bf16x4*)(dst + 4) = f.h[1];
    }
    if (tid < 49) {                                  // output base addresses
        int i = tid / 7, j = tid - 7 * i;
        int r = wh * 7 + i + 3;  if (r >= 56) r -= 56;
        int cc = ww * 7 + j + 3; if (cc >= 56) cc -= 56;
        obase[tid] = ((unsigned)((b * 56 + r) * 56 + cc)) << 8;
    }
    __syncthreads();   // barrier #1 (xw/obase ready; read-only afterwards)

    const f32x4 zf = {0.f, 0.f, 0.f, 0.f};
    const __bf16* wqb = wb + (size_t)(2 * h) * 4096 + lane * 8;  // q tiles 2h,2h+1
    const __bf16* wkb = wqb + 16 * 4096;                          // k tiles +16
    const __bf16* wvb = wqb + 32 * 4096;                          // v tiles +32

    // ---- Phase 1: Q,K GEMM (acc[ct][tt]: ch=16ct+4g+r, tok=16tt+li) ----
    bf16x4 qf[4][2], kf[4][2];   // frags: row=li=tok, k=4g+j=ch(16ct+4g+j)
    {
        f32x4 qa[2][4], ka[2][4];
#pragma unroll
        for (int ct = 0; ct < 2; ++ct)
#pragma unroll
            for (int tt = 0; tt < 4; ++tt) { qa[ct][tt] = zf; ka[ct][tt] = zf; }

#pragma unroll
        for (int kc = 0; kc < 8; ++kc) {
            bf16x8 xf[4];
#pragma unroll
            for (int tt = 0; tt < 4; ++tt) {
                int row = 16 * tt + li; if (row > 48) row = 48;   // clamp pad rows
                xf[tt] = ld8_lds(xw + row * 260 + kc * 32 + g * 8);
            }
#pragma unroll
            for (int ct = 0; ct < 2; ++ct) {
                bf16x8 aq = ld8_gb(wqb + ct * 4096 + kc * 512);
                bf16x8 ak = ld8_gb(wkb + ct * 4096 + kc * 512);
#pragma unroll
                for (int tt = 0; tt < 4; ++tt) {
                    qa[ct][tt] = mfma_k32(aq, xf[tt], qa[ct][tt]);
                    ka[ct][tt] = mfma_k32(ak, xf[tt], ka[ct][tt]);
                }
            }
        }
        // lane-local refragment
#pragma unroll
        for (int ct = 0; ct < 2; ++ct) {
            f32x4 bq = *(const f32x4*)(bqkv + h * 32 + 16 * ct + 4 * g);
            f32x4 bk = *(const f32x4*)(bqkv + 256 + h * 32 + 16 * ct + 4 * g);
#pragma unroll
            for (int tt = 0; tt < 4; ++tt)
#pragma unroll
                for (int r = 0; r < 4; ++r) {
                    qf[tt][ct][r] = (__bf16)((qa[ct][tt][r] + bq[r]) * 0.17677669529663687f);
                    kf[tt][ct][r] = (__bf16)(ka[ct][tt][r] + bk[r]);
                }
        }
    }
    __builtin_amdgcn_sched_barrier(0);   // qa/ka dead before va allocates

    // ---- Phase 2: V GEMM (acc[tt][ct]: tok=16tt+4g+r, ch=16ct+li) ----
    bf16x4 vf[2][4];   // V^T frags [dt][kt]: row=li=d, k=4g+j=key
    {
        f32x4 va[4][2];
#pragma unroll
        for (int tt = 0; tt < 4; ++tt)
#pragma unroll
            for (int ct = 0; ct < 2; ++ct) va[tt][ct] = zf;
#pragma unroll
        for (int kc = 0; kc < 8; ++kc) {
            bf16x8 bv0 = ld8_gb(wvb + kc * 512);
            bf16x8 bv1 = ld8_gb(wvb + 4096 + kc * 512);
#pragma unroll
            for (int tt = 0; tt < 4; ++tt) {
                int row = 16 * tt + li; if (row > 48) row = 48;
                bf16x8 xf = ld8_lds(xw + row * 260 + kc * 32 + g * 8);
                va[tt][0] = mfma_k32(xf, bv0, va[tt][0]);
                va[tt][1] = mfma_k32(xf, bv1, va[tt][1]);
            }
        }
#pragma unroll
        for (int ct = 0; ct < 2; ++ct) {
            float bv = bqkv[512 + h * 32 + 16 * ct + li];
#pragma unroll
            for (int tt = 0; tt < 4; ++tt)
#pragma unroll
                for (int r = 0; r < 4; ++r)
                    vf[ct][tt][r] = (__bf16)(va[tt][ct][r] + bv);
        }
    }
    __builtin_amdgcn_sched_barrier(0);   // va dead before fused loop

    // ---- Phase 3: fused per-qt {S, softmax, PV} ----
    // qt iterations independent -> S/bm-loads of qt+1 overlap softmax/PV of qt
    const float* bmq = bm + cls * 32768 + h * 4096 + lane * 4;
    bf16x4 osv[4][2];  // ctx frags [qt][dt]: q=16qt+4g+r, d=16dt+li
#pragma unroll
    for (int qt = 0; qt < 4; ++qt) {
        f32x4 sv[4];   // S^T frags: lane holds key=16kt+4g+r, q=16qt+li
#pragma unroll
        for (int kt = 0; kt < 4; ++kt) {
            f32x4 acc = *(const f32x4*)(bmq + qt * 1024 + kt * 256);  // bias+mask
            acc = mfma_k16(kf[kt][0], qf[qt][0], acc);
            acc = mfma_k16(kf[kt][1], qf[qt][1], acc);
            sv[kt] = acc;
        }
        float mx = fmaxf(fmaxf(sv[0][0], sv[0][1]), fmaxf(sv[0][2], sv[0][3]));
#pragma unroll
        for (int kt = 1; kt < 4; ++kt)
#pragma unroll
            for (int r = 0; r < 4; ++r) mx = fmaxf(mx, sv[kt][r]);
        mx = fmaxf(mx, __shfl_xor(mx, 16));
        mx = fmaxf(mx, __shfl_xor(mx, 32));
        float sum = 0.f;
#pragma unroll
        for (int kt = 0; kt < 4; ++kt)
#pragma unroll
            for (int r = 0; r < 4; ++r) {
                float e = __expf(sv[kt][r] - mx);
                sv[kt][r] = e;
                sum += e;
            }
        sum += __shfl_xor(sum, 16);
        sum += __shfl_xor(sum, 32);
        float inv = 1.0f / sum;
        bf16x4 pp[4];  // P frags for this qt: row=li=q, k=4g+j=key
#pragma unroll
        for (int kt = 0; kt < 4; ++kt)
#pragma unroll
            for (int r = 0; r < 4; ++r) pp[kt][r] = (__bf16)(sv[kt][r] * inv);
        // PV: oa[dt]: lane holds q=16qt+4g+r, d=16dt+li
#pragma unroll
        for (int dt = 0; dt < 2; ++dt) {
            f32x4 acc = zf;
#pragma unroll
            for (int kt = 0; kt < 4; ++kt)
                acc = mfma_k16(pp[kt], vf[dt][kt], acc);
            osv[qt][dt] = pk4(acc);
        }
    }

    // ---- ctx scatter -> cb ----
#pragma unroll
    for (int qt = 0; qt < 4; ++qt)
#pragma unroll
        for (int r = 0; r < 4; ++r) {
            int q = 16 * qt + 4 * g + r;
            if (q < 49) {
#pragma unroll
                for (int dt = 0; dt < 2; ++dt)
                    cb[q * 260 + 32 * h + 16 * dt + li] = osv[qt][dt][r];
            }
        }
    __syncthreads();   // barrier #2 (ctx complete)

    // ---- proj: 8 waves, wave = (pm: 32 rows, pn: 64 cols) ----
    const int pm = wid >> 2, pn = wid & 3;
    f32x4 pacc[2][4];
#pragma unroll
    for (int mt = 0; mt < 2; ++mt)
#pragma unroll
        for (int nt = 0; nt < 4; ++nt) pacc[mt][nt] = zf;

    const __bf16* wpb = wb + (size_t)(48 + 4 * pn) * 4096 + lane * 8;
#pragma unroll
    for (int kc = 0; kc < 8; ++kc) {
        bf16x8 a[2];
#pragma unroll
        for (int mt = 0; mt < 2; ++mt) {
            int row = 32 * pm + 16 * mt + li; if (row > 48) row = 48;
            a[mt] = ld8_lds(cb + row * 260 + kc * 32 + g * 8);
        }
#pragma unroll
        for (int nt = 0; nt < 4; ++nt) {
            bf16x8 bb = ld8_gb(wpb + nt * 4096 + kc * 512);
#pragma unroll
            for (int mt = 0; mt < 2; ++mt)
                pacc[mt][nt] = mfma_k32(a[mt], bb, pacc[mt][nt]);
        }
    }

    // ---- epilogue: bias + direct fp32 scatter via obase LUT ----
#pragma unroll
    for (int nt = 0; nt < 4; ++nt) {
        int o = 64 * pn + 16 * nt + li;
        float bias = pbias[o];
#pragma unroll
        for (int mt = 0; mt < 2; ++mt)
#pragma unroll
            for (int r = 0; r < 4; ++r) {
                int n = 32 * pm + 16 * mt + 4 * g + r;
                if (n < 49)
                    out[obase[n] + (unsigned)o] = pacc[mt][nt][r] + bias;
            }
    }
}

extern "C" void kernel_launch(void* const* d_in, const int* in_sizes, int n_in,
                              void* d_out, int out_size, void* d_ws, size_t ws_size,
                              hipStream_t stream) {
    const float* x    = (const float*)d_in[0];
    const float* wqkv = (const float*)d_in[1];
    const float* bqkv = (const float*)d_in[2];
    const float* wp   = (const float*)d_in[3];
    const float* pb   = (const float*)d_in[4];
    const float* btab = (const float*)d_in[5];
    float* out = (float*)d_out;

    __bf16* wbuf = (__bf16*)d_ws;                       // 512 KB weights (bf16)
    float* bm = (float*)((char*)d_ws + 524288);         // 512 KB bias+mask table
    k_pre<<<640, 256, 0, stream>>>(wqkv, wp, btab, wbuf, bm);
    k_swin<<<2048, 512, 0, stream>>>(x, wbuf, bqkv, bm, pb, out);
}